// Round 5
// baseline (19233.656 us; speedup 1.0000x reference)
//
#include <hip/hip_runtime.h>
#include <hip/hip_bf16.h>

// RecurrentAE on MI355X — round 5.
//  - 128 unit-WGs x 128 thr (2 waves, 4 M-tiles each): B-frags read once per wave, used 4x
//    -> LDS traffic /4 vs r4. Conflict-free LDS stride 1036 (518 dw == 6 mod 32, b64 reads).
//  - In-register gate epilogue: 4x4 shfl_xor transpose gives each lane all 4 gates of one
//    unit -> no sG LDS tile, single __syncthreads per step.
//  - h stored with a global column permutation (weights pre-permuted to match) so h-stores
//    are contiguous u32 write-through atomics, no shuffles.
//  - Coherence: r4's scheme (per-XCD leader does buffer_inv sc0 sc1 + epoch publish;
//    followers L1-inv only). h rotation depth 4.
//  - Decoder Linear handled by 8 dedicated out-WGs lagging one step (off critical path);
//    leader gates buffer reuse on their progress counter.

#define B_ 128
#define S_ 512
#define F_ 128
#define L_ 1024
#define NWGU 128        // unit WGs (8 hidden units each)
#define NWGO 8          // decoder out-projection WGs (16 out features each)
#define THR 128         // threads per WG (2 waves)
#define WSTR 1036       // LDS row stride (elements): 518 dwords == 6 mod 32
#define XSTR 140        // LDS stride for encoder x tiles (70 dw == 6 mod 32)

typedef __bf16 bf16x8 __attribute__((ext_vector_type(8)));
typedef float  f32x4  __attribute__((ext_vector_type(4)));
typedef unsigned long long u64;

union pk2 { unsigned u; __bf16 h[2]; };
union b8u { u64 q[2]; bf16x8 v; };

// ---------------- workspace layout (bytes) ----------------
#define O_H    0                         // bf16 [4][128][1024] = 1 MB (rotation depth 4)
#define O_H32  (1 << 20)                 // f32 [128][1024] = 512 KB
#define O_CTR  ((1 << 20) + 512 * 1024)  // enc ctr 4 KB @ +0, dec ctr 4 KB @ +4096
#define O_ZERO_END (O_CTR + 8192)
#define O_XB   (O_CTR + 8192)            // bf16 [128][512*128] = 16 MB
#define O_WEH  (O_XB  + 16777216)        // bf16 [128][2][16][1024] = 8 MB
#define O_WEX  (O_WEH + 8388608)         // bf16 [128][2][16][128]  = 1 MB
#define O_BE   (O_WEX + 1048576)         // f32  [128][32]
#define O_WD   (O_BE  + 16384)           // bf16 [128][2][16][1024] = 8 MB
#define O_BD   (O_WD  + 8388608)         // f32  [128][32]
#define O_WO   (O_BD  + 16384)           // bf16 [8][16][1024] = 256 KB
#define O_BO   (O_WO  + 262144)          // f32  [8][16]
#define O_WC   (O_BO  + 512)             // bf16 [3072][1024] = 6 MB (scratch)
// total ~42.8 MB

// column permutation: stored h col p within an 8-block maps to original unit
// orig = (p&~7) + (p&1)*4 + ((p>>1)&3)   (stored order [u0,u4,u1,u5,u2,u6,u3,u7])
__device__ __host__ inline int permk(int k) { return (k & ~7) + (k & 1) * 4 + ((k >> 1) & 3); }

// ---------------- prep kernels ----------------

__global__ void k_xcvt(const float* __restrict__ x, __bf16* __restrict__ xb, int n) {
    int i = blockIdx.x * 256 + threadIdx.x;
    int stride = gridDim.x * 256;
    for (; i < n; i += stride) xb[i] = (__bf16)x[i];
}

// encoder pack: per WG 2 tiles x 16 cols; col = u_in_tile*4 + gate {r,z,ni,nh}; K permuted.
__global__ void k_pack_enc(const float* __restrict__ Wih, const float* __restrict__ Whh,
                           const float* __restrict__ bih, const float* __restrict__ bhh,
                           __bf16* __restrict__ Weh, __bf16* __restrict__ Wex,
                           float* __restrict__ be) {
    int g = blockIdx.x, tid = threadIdx.x;
    for (int i = tid; i < 2 * 16 * 1024; i += 256) {
        int t = i >> 14, rem = i & 16383, tc = rem >> 10, k = rem & 1023;
        int u = g * 8 + t * 4 + (tc >> 2), gate = tc & 3;
        int o = permk(k);
        float v = 0.f;
        if (gate == 0)      v = Whh[(size_t)u * 1024 + o];
        else if (gate == 1) v = Whh[(size_t)(1024 + u) * 1024 + o];
        else if (gate == 3) v = Whh[(size_t)(2048 + u) * 1024 + o];
        Weh[((size_t)(g * 2 + t) * 16 + tc) * 1024 + k] = (__bf16)v;
    }
    for (int i = tid; i < 2 * 16 * 128; i += 256) {
        int t = i >> 11, rem = i & 2047, tc = rem >> 7, k = rem & 127;
        int u = g * 8 + t * 4 + (tc >> 2), gate = tc & 3;
        float v = 0.f;
        if (gate == 0)      v = Wih[(size_t)u * 128 + k];
        else if (gate == 1) v = Wih[(size_t)(1024 + u) * 128 + k];
        else if (gate == 2) v = Wih[(size_t)(2048 + u) * 128 + k];
        Wex[((size_t)(g * 2 + t) * 16 + tc) * 128 + k] = (__bf16)v;
    }
    if (tid < 32) {
        int c = tid, u = g * 8 + (c >> 4) * 4 + ((c >> 2) & 3), gate = c & 3;
        float v;
        if (gate == 0)      v = bih[u] + bhh[u];
        else if (gate == 1) v = bih[1024 + u] + bhh[1024 + u];
        else if (gate == 2) v = bih[2048 + u];
        else                v = bhh[2048 + u];
        be[g * 32 + c] = v;
    }
}

// W_comb = W_ih_d @ W_out (bf16, original K indexing; perm applied at pack_dec read)
__global__ void k_wcomb(const float* __restrict__ Wihd, const float* __restrict__ Wout,
                        __bf16* __restrict__ Wc) {
    __shared__ float a[8][128];
    int r0 = blockIdx.x * 8, tid = threadIdx.x;
    for (int i = tid; i < 8 * 128; i += 256)
        a[i >> 7][i & 127] = Wihd[(size_t)(r0 + (i >> 7)) * 128 + (i & 127)];
    __syncthreads();
    for (int j = tid; j < 1024; j += 256) {
        float acc[8] = {0, 0, 0, 0, 0, 0, 0, 0};
        for (int f = 0; f < 128; ++f) {
            float w = Wout[(size_t)f * 1024 + j];
#pragma unroll
            for (int r = 0; r < 8; ++r) acc[r] += a[r][f] * w;
        }
        for (int r = 0; r < 8; ++r) Wc[(size_t)(r0 + r) * 1024 + j] = (__bf16)acc[r];
    }
}

// decoder pack: gates {r:Whh+Wc, z:Whh+Wc, ni:Wc, nh:Whh}; K permuted; bias folds Wihd@bout.
__global__ void k_pack_dec(const float* __restrict__ Whhd, const __bf16* __restrict__ Wc,
                           const float* __restrict__ Wihd, const float* __restrict__ bihd,
                           const float* __restrict__ bhhd, const float* __restrict__ bout,
                           __bf16* __restrict__ Wd, float* __restrict__ bd) {
    int g = blockIdx.x, tid = threadIdx.x;
    for (int i = tid; i < 2 * 16 * 1024; i += 256) {
        int t = i >> 14, rem = i & 16383, tc = rem >> 10, k = rem & 1023;
        int u = g * 8 + t * 4 + (tc >> 2), gate = tc & 3;
        int o = permk(k);
        float v;
        if (gate == 0)      v = Whhd[(size_t)u * 1024 + o] + (float)Wc[(size_t)u * 1024 + o];
        else if (gate == 1) v = Whhd[(size_t)(1024 + u) * 1024 + o] + (float)Wc[(size_t)(1024 + u) * 1024 + o];
        else if (gate == 2) v = (float)Wc[(size_t)(2048 + u) * 1024 + o];
        else                v = Whhd[(size_t)(2048 + u) * 1024 + o];
        Wd[((size_t)(g * 2 + t) * 16 + tc) * 1024 + k] = (__bf16)v;
    }
    if (tid < 32) {
        int c = tid, u = g * 8 + (c >> 4) * 4 + ((c >> 2) & 3), gate = c & 3;
        int row = (gate == 0) ? u : (gate == 1) ? (1024 + u) : (2048 + u);
        float v;
        if (gate <= 2) {
            float d = 0.f;
            for (int f = 0; f < 128; ++f) d += Wihd[(size_t)row * 128 + f] * bout[f];
            v = d + bihd[row] + ((gate <= 1) ? bhhd[row] : 0.f);
        } else {
            v = bhhd[row];
        }
        bd[g * 32 + c] = v;
    }
}

// out-projection pack: Wo[og][16][1024] (K permuted), bo[og][16]
__global__ void k_pack_out(const float* __restrict__ Wout, const float* __restrict__ bout,
                           __bf16* __restrict__ Wo, float* __restrict__ bo) {
    int og = blockIdx.x, tid = threadIdx.x;
    for (int i = tid; i < 16 * 1024; i += 256) {
        int fl = i >> 10, k = i & 1023;
        Wo[((size_t)og * 16 + fl) * 1024 + k] = (__bf16)Wout[(size_t)(og * 16 + fl) * 1024 + permk(k)];
    }
    if (tid < 16) bo[og * 16 + tid] = bout[og * 16 + tid];
}

// ---------------- sync primitives (r4 scheme) ----------------
// ctr block (u32 idx): subs j*32 (j<8); out-line 256; epoch 512+xcd*32; claim 768+xcd*32.
__device__ __forceinline__ unsigned ld_u32(const unsigned* p) {
    return __hip_atomic_load(p, __ATOMIC_RELAXED, __HIP_MEMORY_SCOPE_AGENT);
}
__device__ __forceinline__ void elect(unsigned* base, bool claim, int& xcd, bool& lead) {
    if (threadIdx.x == 0) {
        int x;
        asm volatile("s_getreg_b32 %0, hwreg(HW_REG_XCC_ID)" : "=s"(x));
        xcd = x & 7;
        lead = false;
        if (claim) {
            unsigned old = __hip_atomic_fetch_add(base + 768 + xcd * 32, 1u,
                                                  __ATOMIC_RELAXED, __HIP_MEMORY_SCOPE_AGENT);
            lead = (old == 0);
        }
    }
}
__device__ __forceinline__ void bar_arrive(unsigned* base, int g) {
    if (threadIdx.x == 0)
        __hip_atomic_fetch_add(base + (g & 7) * 32, 1u, __ATOMIC_RELAXED, __HIP_MEMORY_SCOPE_AGENT);
}
// leader: poll unit arrivals (+ optional out progress), L2+L1 inv, publish epoch=ustep.
// follower: poll epoch, L1 inv.
__device__ __forceinline__ void bar_wait(unsigned* base, int xcd, bool lead,
                                         unsigned ustep, unsigned otgt) {
    if (threadIdx.x == 0) {
        if (lead) {
            unsigned utgt = ustep * NWGU;
            for (;;) {
                unsigned s = 0;
#pragma unroll
                for (int j = 0; j < 8; ++j) s += ld_u32(base + j * 32);
                if (s >= utgt && (otgt == 0 || ld_u32(base + 256) >= otgt)) break;
                __builtin_amdgcn_s_sleep(1);
            }
            asm volatile("buffer_inv sc0 sc1\ns_waitcnt vmcnt(0)" ::: "memory");
            __hip_atomic_store(base + 512 + xcd * 32, ustep,
                               __ATOMIC_RELAXED, __HIP_MEMORY_SCOPE_AGENT);
        } else {
            while (ld_u32(base + 512 + xcd * 32) < ustep) __builtin_amdgcn_s_sleep(1);
            asm volatile("buffer_inv sc0\ns_waitcnt vmcnt(0)" ::: "memory");
        }
    }
    __syncthreads();
}

#define MFMA16(a, b, c) __builtin_amdgcn_mfma_f32_16x16x32_bf16(a, b, c, 0, 0, 0)

// ---------------- encoder ----------------
__global__ __launch_bounds__(THR, 1) void k_enc(
    const __bf16* __restrict__ xb, const __bf16* __restrict__ Weh,
    const __bf16* __restrict__ Wex, const float* __restrict__ be,
    __bf16* __restrict__ hb, float* __restrict__ h32, unsigned* __restrict__ ctr) {
    __shared__ __bf16 sWh[2][16][WSTR];
    __shared__ __bf16 sWx[2][16][XSTR];
    const int g = blockIdx.x, tid = threadIdx.x;
    const int lane = tid & 63, wv = tid >> 6;
    const int tcol = lane & 15, quad = lane >> 4, kq = quad * 8;
    const int q = tcol >> 2, jr = tcol & 3;

    int xcd = 0; bool lead = false;
    elect(ctr, true, xcd, lead);

    for (int i = tid; i < 8192; i += THR) {       // 2*16*1024 elems, u64 chunks
        int t = i >> 12, rem = i & 4095, tc = rem >> 8, k4 = rem & 255;
        *(u64*)&sWh[t][tc][k4 * 4] = *(const u64*)(Weh + ((size_t)(g * 2 + t) * 16 + tc) * 1024 + k4 * 4);
    }
    for (int i = tid; i < 1024; i += THR) {       // 2*16*128 elems, u64 chunks
        int t = i >> 9, rem = i & 511, tc = rem >> 5, k4 = rem & 31;
        *(u64*)&sWx[t][tc][k4 * 4] = *(const u64*)(Wex + ((size_t)(g * 2 + t) * 16 + tc) * 128 + k4 * 4);
    }
    float bR[2], bZ[2], bNI[2], bNH[2];
#pragma unroll
    for (int t = 0; t < 2; ++t) {
        int cb = g * 32 + t * 16 + (tcol & 12);
        bR[t] = be[cb]; bZ[t] = be[cb + 1]; bNI[t] = be[cb + 2]; bNH[t] = be[cb + 3];
    }
    __syncthreads();

    int rowA[4], rowE[4];
#pragma unroll
    for (int m = 0; m < 4; ++m) {
        rowA[m] = wv * 64 + m * 16 + tcol;
        rowE[m] = wv * 64 + m * 16 + 4 * quad + jr;
    }
    float hprev[4][2] = {{0.f, 0.f}, {0.f, 0.f}, {0.f, 0.f}, {0.f, 0.f}};
    f32x4 acc[4][2];

    auto ldsb = [&](int t, int kt) -> bf16x8 {
        b8u u;
        const __bf16* p = &sWh[t][tcol][kt * 32 + kq];
        u.q[0] = *(const u64*)p; u.q[1] = *(const u64*)(p + 4);
        return u.v;
    };
    auto xwin = [&](int s) {   // x-part of step s (K=128) -> acc init
#pragma unroll
        for (int m = 0; m < 4; ++m) { acc[m][0] = f32x4{0, 0, 0, 0}; acc[m][1] = f32x4{0, 0, 0, 0}; }
#pragma unroll
        for (int kt = 0; kt < 4; ++kt) {
            b8u b0, b1;
            const __bf16* p0 = &sWx[0][tcol][kt * 32 + kq];
            const __bf16* p1 = &sWx[1][tcol][kt * 32 + kq];
            b0.q[0] = *(const u64*)p0; b0.q[1] = *(const u64*)(p0 + 4);
            b1.q[0] = *(const u64*)p1; b1.q[1] = *(const u64*)(p1 + 4);
#pragma unroll
            for (int m = 0; m < 4; ++m) {
                bf16x8 a = *(const bf16x8*)(xb + (size_t)rowA[m] * 65536 + s * 128 + kt * 32 + kq);
                acc[m][0] = MFMA16(a, b0.v, acc[m][0]);
                acc[m][1] = MFMA16(a, b1.v, acc[m][1]);
            }
        }
    };
    auto tp4 = [&](f32x4& a) {   // 4x4 transpose across lanes (tcol&3) x regs
        bool s0 = tcol & 1, s1 = tcol & 2;
        float v;
        v = __shfl_xor(s0 ? a[0] : a[1], 1); if (s0) a[0] = v; else a[1] = v;
        v = __shfl_xor(s0 ? a[2] : a[3], 1); if (s0) a[2] = v; else a[3] = v;
        v = __shfl_xor(s1 ? a[0] : a[2], 2); if (s1) a[0] = v; else a[2] = v;
        v = __shfl_xor(s1 ? a[1] : a[3], 2); if (s1) a[1] = v; else a[3] = v;
    };

    xwin(0);
    for (int s = 0; s < 512; ++s) {
        const __bf16* hcur = hb + (size_t)(s & 3) * 131072;
        unsigned* hnx = (unsigned*)(hb + (size_t)((s + 1) & 3) * 131072);
#pragma unroll 4
        for (int kt = 0; kt < 32; ++kt) {
            bf16x8 b0 = ldsb(0, kt), b1 = ldsb(1, kt);
#pragma unroll
            for (int m = 0; m < 4; ++m) {
                bf16x8 a = *(const bf16x8*)(hcur + (size_t)rowA[m] * 1024 + kt * 32 + kq);
                acc[m][0] = MFMA16(a, b0, acc[m][0]);
                acc[m][1] = MFMA16(a, b1, acc[m][1]);
            }
        }
#pragma unroll
        for (int m = 0; m < 4; ++m) {
            tp4(acc[m][0]); tp4(acc[m][1]);
            pk2 p;
#pragma unroll
            for (int t = 0; t < 2; ++t) {
                float r = 1.f / (1.f + __expf(-(acc[m][t][0] + bR[t])));
                float z = 1.f / (1.f + __expf(-(acc[m][t][1] + bZ[t])));
                float n = tanhf(acc[m][t][2] + bNI[t] + r * (acc[m][t][3] + bNH[t]));
                float h = (1.f - z) * n + z * hprev[m][t];
                hprev[m][t] = h;
                p.h[t] = (__bf16)h;
            }
            __hip_atomic_store(hnx + rowE[m] * 512 + g * 4 + q, p.u,
                               __ATOMIC_RELAXED, __HIP_MEMORY_SCOPE_AGENT);
        }
        if (s < 511) {
            __syncthreads();                 // drain write-through h stores
            bar_arrive(ctr, g);
            xwin(s + 1);                     // overlap x-GEMM with grid convergence
            bar_wait(ctr, xcd, lead, (unsigned)(s + 1), 0);
        }
    }
    // fp32 handoff
#pragma unroll
    for (int m = 0; m < 4; ++m)
#pragma unroll
        for (int t = 0; t < 2; ++t)
            __hip_atomic_store(h32 + rowE[m] * 1024 + g * 8 + q * 2 + t, hprev[m][t],
                               __ATOMIC_RELAXED, __HIP_MEMORY_SCOPE_AGENT);
}

// ---------------- decoder (128 unit WGs + 8 out WGs) ----------------
__global__ __launch_bounds__(THR, 1) void k_dec(
    const __bf16* __restrict__ Wd, const float* __restrict__ bd,
    const __bf16* __restrict__ Wo, const float* __restrict__ bo,
    __bf16* __restrict__ hb, const float* __restrict__ h32,
    float* __restrict__ out, unsigned* __restrict__ ctr) {
    __shared__ __bf16 sWh[2][16][WSTR];
    const int g = blockIdx.x, tid = threadIdx.x;
    const int lane = tid & 63, wv = tid >> 6;
    const int tcol = lane & 15, quad = lane >> 4, kq = quad * 8;
    const int q = tcol >> 2, jr = tcol & 3;
    const bool isunit = (g < NWGU);

    int xcd = 0; bool lead = false;
    elect(ctr, isunit, xcd, lead);

    int rowA[4];
#pragma unroll
    for (int m = 0; m < 4; ++m) rowA[m] = wv * 64 + m * 16 + tcol;

    auto ldsb = [&](int t, int kt) -> bf16x8 {
        b8u u;
        const __bf16* p = &sWh[t][tcol][kt * 32 + kq];
        u.q[0] = *(const u64*)p; u.q[1] = *(const u64*)(p + 4);
        return u.v;
    };

    if (isunit) {
        for (int i = tid; i < 8192; i += THR) {
            int t = i >> 12, rem = i & 4095, tc = rem >> 8, k4 = rem & 255;
            *(u64*)&sWh[t][tc][k4 * 4] = *(const u64*)(Wd + ((size_t)(g * 2 + t) * 16 + tc) * 1024 + k4 * 4);
        }
        float bR[2], bZ[2], bNI[2], bNH[2];
#pragma unroll
        for (int t = 0; t < 2; ++t) {
            int cb = g * 32 + t * 16 + (tcol & 12);
            bR[t] = bd[cb]; bZ[t] = bd[cb + 1]; bNI[t] = bd[cb + 2]; bNH[t] = bd[cb + 3];
        }
        int rowE[4];
#pragma unroll
        for (int m = 0; m < 4; ++m) rowE[m] = wv * 64 + m * 16 + 4 * quad + jr;
        float hprev[4][2];
#pragma unroll
        for (int m = 0; m < 4; ++m)
#pragma unroll
            for (int t = 0; t < 2; ++t)
                hprev[m][t] = __hip_atomic_load(h32 + rowE[m] * 1024 + g * 8 + q * 2 + t,
                                                __ATOMIC_RELAXED, __HIP_MEMORY_SCOPE_AGENT);
        __syncthreads();

        auto tp4 = [&](f32x4& a) {
            bool s0 = tcol & 1, s1 = tcol & 2;
            float v;
            v = __shfl_xor(s0 ? a[0] : a[1], 1); if (s0) a[0] = v; else a[1] = v;
            v = __shfl_xor(s0 ? a[2] : a[3], 1); if (s0) a[2] = v; else a[3] = v;
            v = __shfl_xor(s1 ? a[0] : a[2], 2); if (s1) a[0] = v; else a[2] = v;
            v = __shfl_xor(s1 ? a[1] : a[3], 2); if (s1) a[1] = v; else a[3] = v;
        };

        for (int s = 0; s < 512; ++s) {
            if (s > 0) {
                // out-WGs lag <=1 step; gate rewrite of buf[(s+1)&3] (held h_{s-3}) on
                // out-step s-4 completion: outsum >= 8*(s-3).
                unsigned otgt = (s >= 4) ? (unsigned)(NWGO * (s - 3)) : 0u;
                bar_wait(ctr, xcd, lead, (unsigned)s, otgt);
            }
            const __bf16* hcur = hb + (size_t)(s & 3) * 131072;
            unsigned* hnx = (unsigned*)(hb + (size_t)((s + 1) & 3) * 131072);
            f32x4 acc[4][2];
#pragma unroll
            for (int m = 0; m < 4; ++m) { acc[m][0] = f32x4{0, 0, 0, 0}; acc[m][1] = f32x4{0, 0, 0, 0}; }
#pragma unroll 4
            for (int kt = 0; kt < 32; ++kt) {
                bf16x8 b0 = ldsb(0, kt), b1 = ldsb(1, kt);
#pragma unroll
                for (int m = 0; m < 4; ++m) {
                    bf16x8 a = *(const bf16x8*)(hcur + (size_t)rowA[m] * 1024 + kt * 32 + kq);
                    acc[m][0] = MFMA16(a, b0, acc[m][0]);
                    acc[m][1] = MFMA16(a, b1, acc[m][1]);
                }
            }
#pragma unroll
            for (int m = 0; m < 4; ++m) {
                tp4(acc[m][0]); tp4(acc[m][1]);
                pk2 p;
#pragma unroll
                for (int t = 0; t < 2; ++t) {
                    float r = 1.f / (1.f + __expf(-(acc[m][t][0] + bR[t])));
                    float z = 1.f / (1.f + __expf(-(acc[m][t][1] + bZ[t])));
                    float n = tanhf(acc[m][t][2] + bNI[t] + r * (acc[m][t][3] + bNH[t]));
                    float h = (1.f - z) * n + z * hprev[m][t];
                    hprev[m][t] = h;
                    p.h[t] = (__bf16)h;
                }
                __hip_atomic_store(hnx + rowE[m] * 512 + g * 4 + q, p.u,
                                   __ATOMIC_RELAXED, __HIP_MEMORY_SCOPE_AGENT);
            }
            __syncthreads();                 // drain h stores
            bar_arrive(ctr, g);
        }
        // publish final epoch so lagging out-WGs can read h_512
        if (tid == 0 && lead) {
            for (;;) {
                unsigned sum = 0;
#pragma unroll
                for (int j = 0; j < 8; ++j) sum += ld_u32(ctr + j * 32);
                if (sum >= (unsigned)(NWGU * 512)) break;
                __builtin_amdgcn_s_sleep(1);
            }
            asm volatile("buffer_inv sc0 sc1\ns_waitcnt vmcnt(0)" ::: "memory");
            __hip_atomic_store(ctr + 512 + xcd * 32, 512u,
                               __ATOMIC_RELAXED, __HIP_MEMORY_SCOPE_AGENT);
        }
    } else {
        // ---- out-projection WG: lags one step, off the critical path ----
        const int og = g - NWGU;
        for (int i = tid; i < 4096; i += THR) {   // 16*1024 elems, u64 chunks
            int tc = i >> 8, k4 = i & 255;
            *(u64*)&sWh[0][tc][k4 * 4] = *(const u64*)(Wo + ((size_t)og * 16 + tc) * 1024 + k4 * 4);
        }
        const float bo_ = bo[og * 16 + tcol];
        __syncthreads();

        for (int s = 0; s < 512; ++s) {
            if (tid == 0) {   // wait h_{s+1} published on this XCD, then L1 inv
                while (ld_u32(ctr + 512 + xcd * 32) < (unsigned)(s + 1)) __builtin_amdgcn_s_sleep(1);
                asm volatile("buffer_inv sc0\ns_waitcnt vmcnt(0)" ::: "memory");
            }
            __syncthreads();
            const __bf16* hcur = hb + (size_t)((s + 1) & 3) * 131072;
            f32x4 acc[4];
#pragma unroll
            for (int m = 0; m < 4; ++m) acc[m] = f32x4{0, 0, 0, 0};
#pragma unroll 4
            for (int kt = 0; kt < 32; ++kt) {
                bf16x8 b0 = ldsb(0, kt);
#pragma unroll
                for (int m = 0; m < 4; ++m) {
                    bf16x8 a = *(const bf16x8*)(hcur + (size_t)rowA[m] * 1024 + kt * 32 + kq);
                    acc[m] = MFMA16(a, b0, acc[m]);
                }
            }
            __syncthreads();                 // all reads of h_{s+1} done
            if (tid == 0)
                __hip_atomic_fetch_add(ctr + 256, 1u, __ATOMIC_RELAXED, __HIP_MEMORY_SCOPE_AGENT);
            // out[:, 511-s, :] = h_{s+1} @ Wout^T + bout  (write-through, inv-safe)
#pragma unroll
            for (int m = 0; m < 4; ++m)
#pragma unroll
                for (int i = 0; i < 4; ++i) {
                    int row = wv * 64 + m * 16 + 4 * quad + i;
                    float v = acc[m][i] + bo_;
                    __hip_atomic_store(out + (size_t)row * 65536 + (size_t)(511 - s) * 128 + og * 16 + tcol,
                                       v, __ATOMIC_RELAXED, __HIP_MEMORY_SCOPE_AGENT);
                }
        }
    }
}

// ---------------- launch ----------------
extern "C" void kernel_launch(void* const* d_in, const int* in_sizes, int n_in,
                              void* d_out, int out_size, void* d_ws, size_t ws_size,
                              hipStream_t stream) {
    (void)in_sizes; (void)n_in; (void)out_size; (void)ws_size;
    const float* x    = (const float*)d_in[0];
    const float* Wihe = (const float*)d_in[1];
    const float* Whhe = (const float*)d_in[2];
    const float* bihe = (const float*)d_in[3];
    const float* bhhe = (const float*)d_in[4];
    const float* Wihd = (const float*)d_in[5];
    const float* Whhd = (const float*)d_in[6];
    const float* bihd = (const float*)d_in[7];
    const float* bhhd = (const float*)d_in[8];
    const float* Wout = (const float*)d_in[9];
    const float* bout = (const float*)d_in[10];

    char* ws = (char*)d_ws;
    __bf16*   hb  = (__bf16*)(ws + O_H);
    float*    h32 = (float*)(ws + O_H32);
    unsigned* ctr = (unsigned*)(ws + O_CTR);
    __bf16*   xbf = (__bf16*)(ws + O_XB);
    __bf16*   Weh = (__bf16*)(ws + O_WEH);
    __bf16*   Wex = (__bf16*)(ws + O_WEX);
    float*    be  = (float*)(ws + O_BE);
    __bf16*   Wd  = (__bf16*)(ws + O_WD);
    float*    bd  = (float*)(ws + O_BD);
    __bf16*   Wo  = (__bf16*)(ws + O_WO);
    float*    bo  = (float*)(ws + O_BO);
    __bf16*   Wc  = (__bf16*)(ws + O_WC);

    hipMemsetAsync(ws, 0, O_ZERO_END, stream);   // h rotation bufs + h32 + sync blocks

    k_xcvt<<<4096, 256, 0, stream>>>(x, xbf, B_ * S_ * F_);
    k_pack_enc<<<NWGU, 256, 0, stream>>>(Wihe, Whhe, bihe, bhhe, Weh, Wex, be);
    k_wcomb<<<384, 256, 0, stream>>>(Wihd, Wout, Wc);
    k_pack_dec<<<NWGU, 256, 0, stream>>>(Whhd, Wc, Wihd, bihd, bhhd, bout, Wd, bd);
    k_pack_out<<<NWGO, 256, 0, stream>>>(Wout, bout, Wo, bo);

    k_enc<<<NWGU, THR, 0, stream>>>(xbf, Weh, Wex, be, hb, h32, ctr);
    k_dec<<<NWGU + NWGO, THR, 0, stream>>>(Wd, bd, Wo, bo, hb, h32, (float*)d_out, ctr + 1024);
}

// Round 6
// 10832.063 us; speedup vs baseline: 1.7756x; 1.7756x over previous
//
#include <hip/hip_runtime.h>
#include <hip/hip_bf16.h>

// RecurrentAE on MI355X — round 6.
//  - r4's 8-wave structure (128 WGs x 512 thr, weights in LDS, wave = 1 M-tile x 2 N-tiles)
//    + r5's validated fixes: conflict-free LDS stride 1036, in-register tp4 gate epilogue
//    (no sG tile, one __syncthreads/step), permuted contiguous u32 h-stores.
//  - NEW: write-once h ring (513 slots x 256 KB). h_s lives at its own address forever ->
//    consumer L2s can never hold a stale copy -> plain cached h loads with ZERO per-step
//    cache maintenance (no buffer_inv, no leader, no epoch). Producers write through to LLC
//    (relaxed agent atomics); first reader per XCD cold-fills L2 from LLC = the broadcast.
//  - Barrier: 16 relaxed sub-lines, every WG polls the sum itself (radius-free, no hops).
//  - Decoder Linear: W_comb fusion (as r1-r5) + out-cols as a 3rd N-tile on WGs 0..7,
//    computed from the same A-fragments; one extra out-only pass for h_512.

#define B_ 128
#define S_ 512
#define NWG 128
#define THR 512
#define WSTR 1036       // LDS row stride (elems): 518 dw == 6 mod 32 -> conflict-free b64
#define XSTR 140        // 70 dw == 6 mod 32
#define SLOT 131072     // bf16 elems per ring slot (128 rows x 1024)

typedef __bf16 bf16x8 __attribute__((ext_vector_type(8)));
typedef float  f32x4  __attribute__((ext_vector_type(4)));
typedef unsigned long long u64;

union pk2 { unsigned u; __bf16 h[2]; };
union b8u { u64 q[2]; bf16x8 v; };

// ---------------- workspace layout (bytes) ----------------
#define O_RING 0
#define RING_BYTES (513ull * 262144ull)      // 134,479,872
#define O_H32  ((size_t)RING_BYTES)          // f32 [128][1024]
#define O_CTR  (O_H32 + 524288)              // enc 4 KB @ +0, dec 4 KB @ +4096
#define O_XB   (O_CTR + 8192)                // bf16 [128][512*128] = 16 MB
#define O_WEH  (O_XB  + 16777216)            // bf16 [128][2][16][1024] = 8 MB
#define O_WEX  (O_WEH + 8388608)             // bf16 [128][2][16][128]  = 1 MB
#define O_BE   (O_WEX + 1048576)             // f32  [128][32]
#define O_WD   (O_BE  + 16384)               // bf16 [128][2][16][1024] = 8 MB
#define O_BD   (O_WD  + 8388608)             // f32  [128][32]
#define O_WO   (O_BD  + 16384)               // bf16 [8][16][1024] = 256 KB
#define O_BO   (O_WO  + 262144)              // f32  [8][16]
#define O_WC   (O_BO  + 512)                 // bf16 [3072][1024] = 6 MB (prep scratch)
// total ~176 MB

// stored-h column permutation within each 8-unit block: [u0,u4,u1,u5,u2,u6,u3,u7]
__device__ __host__ inline int permk(int k) { return (k & ~7) + (k & 1) * 4 + ((k >> 1) & 3); }

// ---------------- prep kernels (validated in r5) ----------------

__global__ void k_xcvt(const float* __restrict__ x, __bf16* __restrict__ xb, int n) {
    int i = blockIdx.x * 256 + threadIdx.x;
    int stride = gridDim.x * 256;
    for (; i < n; i += stride) xb[i] = (__bf16)x[i];
}

__global__ void k_pack_enc(const float* __restrict__ Wih, const float* __restrict__ Whh,
                           const float* __restrict__ bih, const float* __restrict__ bhh,
                           __bf16* __restrict__ Weh, __bf16* __restrict__ Wex,
                           float* __restrict__ be) {
    int g = blockIdx.x, tid = threadIdx.x;
    for (int i = tid; i < 2 * 16 * 1024; i += 256) {
        int t = i >> 14, rem = i & 16383, tc = rem >> 10, k = rem & 1023;
        int u = g * 8 + t * 4 + (tc >> 2), gate = tc & 3;
        int o = permk(k);
        float v = 0.f;
        if (gate == 0)      v = Whh[(size_t)u * 1024 + o];
        else if (gate == 1) v = Whh[(size_t)(1024 + u) * 1024 + o];
        else if (gate == 3) v = Whh[(size_t)(2048 + u) * 1024 + o];
        Weh[((size_t)(g * 2 + t) * 16 + tc) * 1024 + k] = (__bf16)v;
    }
    for (int i = tid; i < 2 * 16 * 128; i += 256) {
        int t = i >> 11, rem = i & 2047, tc = rem >> 7, k = rem & 127;
        int u = g * 8 + t * 4 + (tc >> 2), gate = tc & 3;
        float v = 0.f;
        if (gate == 0)      v = Wih[(size_t)u * 128 + k];
        else if (gate == 1) v = Wih[(size_t)(1024 + u) * 128 + k];
        else if (gate == 2) v = Wih[(size_t)(2048 + u) * 128 + k];
        Wex[((size_t)(g * 2 + t) * 16 + tc) * 128 + k] = (__bf16)v;
    }
    if (tid < 32) {
        int c = tid, u = g * 8 + (c >> 4) * 4 + ((c >> 2) & 3), gate = c & 3;
        float v;
        if (gate == 0)      v = bih[u] + bhh[u];
        else if (gate == 1) v = bih[1024 + u] + bhh[1024 + u];
        else if (gate == 2) v = bih[2048 + u];
        else                v = bhh[2048 + u];
        be[g * 32 + c] = v;
    }
}

__global__ void k_wcomb(const float* __restrict__ Wihd, const float* __restrict__ Wout,
                        __bf16* __restrict__ Wc) {
    __shared__ float a[8][128];
    int r0 = blockIdx.x * 8, tid = threadIdx.x;
    for (int i = tid; i < 8 * 128; i += 256)
        a[i >> 7][i & 127] = Wihd[(size_t)(r0 + (i >> 7)) * 128 + (i & 127)];
    __syncthreads();
    for (int j = tid; j < 1024; j += 256) {
        float acc[8] = {0, 0, 0, 0, 0, 0, 0, 0};
        for (int f = 0; f < 128; ++f) {
            float w = Wout[(size_t)f * 1024 + j];
#pragma unroll
            for (int r = 0; r < 8; ++r) acc[r] += a[r][f] * w;
        }
        for (int r = 0; r < 8; ++r) Wc[(size_t)(r0 + r) * 1024 + j] = (__bf16)acc[r];
    }
}

__global__ void k_pack_dec(const float* __restrict__ Whhd, const __bf16* __restrict__ Wc,
                           const float* __restrict__ Wihd, const float* __restrict__ bihd,
                           const float* __restrict__ bhhd, const float* __restrict__ bout,
                           __bf16* __restrict__ Wd, float* __restrict__ bd) {
    int g = blockIdx.x, tid = threadIdx.x;
    for (int i = tid; i < 2 * 16 * 1024; i += 256) {
        int t = i >> 14, rem = i & 16383, tc = rem >> 10, k = rem & 1023;
        int u = g * 8 + t * 4 + (tc >> 2), gate = tc & 3;
        int o = permk(k);
        float v;
        if (gate == 0)      v = Whhd[(size_t)u * 1024 + o] + (float)Wc[(size_t)u * 1024 + o];
        else if (gate == 1) v = Whhd[(size_t)(1024 + u) * 1024 + o] + (float)Wc[(size_t)(1024 + u) * 1024 + o];
        else if (gate == 2) v = (float)Wc[(size_t)(2048 + u) * 1024 + o];
        else                v = Whhd[(size_t)(2048 + u) * 1024 + o];
        Wd[((size_t)(g * 2 + t) * 16 + tc) * 1024 + k] = (__bf16)v;
    }
    if (tid < 32) {
        int c = tid, u = g * 8 + (c >> 4) * 4 + ((c >> 2) & 3), gate = c & 3;
        int row = (gate == 0) ? u : (gate == 1) ? (1024 + u) : (2048 + u);
        float v;
        if (gate <= 2) {
            float d = 0.f;
            for (int f = 0; f < 128; ++f) d += Wihd[(size_t)row * 128 + f] * bout[f];
            v = d + bihd[row] + ((gate <= 1) ? bhhd[row] : 0.f);
        } else {
            v = bhhd[row];
        }
        bd[g * 32 + c] = v;
    }
}

__global__ void k_pack_out(const float* __restrict__ Wout, const float* __restrict__ bout,
                           __bf16* __restrict__ Wo, float* __restrict__ bo) {
    int og = blockIdx.x, tid = threadIdx.x;
    for (int i = tid; i < 16 * 1024; i += 256) {
        int fl = i >> 10, k = i & 1023;
        Wo[((size_t)og * 16 + fl) * 1024 + k] = (__bf16)Wout[(size_t)(og * 16 + fl) * 1024 + permk(k)];
    }
    if (tid < 16) bo[og * 16 + tid] = bout[og * 16 + tid];
}

// ---------------- barrier: 16 sub-lines, self-polled sum, no fences ----------------
__device__ __forceinline__ unsigned ld_u32(const unsigned* p) {
    return __hip_atomic_load(p, __ATOMIC_RELAXED, __HIP_MEMORY_SCOPE_AGENT);
}
__device__ __forceinline__ void bar_arrive(unsigned* c, int g) {
    if (threadIdx.x == 0)
        __hip_atomic_fetch_add(c + (g & 15) * 32, 1u, __ATOMIC_RELAXED, __HIP_MEMORY_SCOPE_AGENT);
}
__device__ __forceinline__ void bar_wait(unsigned* c, unsigned tgt) {
    if (threadIdx.x == 0) {
        for (;;) {
            unsigned s = 0;
#pragma unroll
            for (int j = 0; j < 16; ++j) s += ld_u32(c + j * 32);
            if (s >= tgt) break;
            __builtin_amdgcn_s_sleep(1);
        }
    }
    __syncthreads();
}

#define MFMA16(a, b, c) __builtin_amdgcn_mfma_f32_16x16x32_bf16(a, b, c, 0, 0, 0)

// ---------------- encoder ----------------
__global__ __launch_bounds__(THR, 1) void k_enc(
    const __bf16* __restrict__ xb, const __bf16* __restrict__ Weh,
    const __bf16* __restrict__ Wex, const float* __restrict__ be,
    __bf16* __restrict__ ring, float* __restrict__ h32, unsigned* __restrict__ ctr) {
    __shared__ __bf16 sWh[2][16][WSTR];
    __shared__ __bf16 sWx[2][16][XSTR];
    const int g = blockIdx.x, tid = threadIdx.x;
    const int lane = tid & 63, wv = tid >> 6;
    const int tcol = lane & 15, quad = lane >> 4, kq = quad * 8;
    const int q = tcol >> 2, jr = tcol & 3;

    for (int i = tid; i < 8192; i += THR) {          // 2*16*1024 elems, u64 chunks
        int t = i >> 12, rem = i & 4095, tc = rem >> 8, k4 = rem & 255;
        *(u64*)&sWh[t][tc][k4 * 4] = *(const u64*)(Weh + ((size_t)(g * 2 + t) * 16 + tc) * 1024 + k4 * 4);
    }
    for (int i = tid; i < 1024; i += THR) {          // 2*16*128 elems
        int t = i >> 9, rem = i & 511, tc = rem >> 5, k4 = rem & 31;
        *(u64*)&sWx[t][tc][k4 * 4] = *(const u64*)(Wex + ((size_t)(g * 2 + t) * 16 + tc) * 128 + k4 * 4);
    }
    float bR[2], bZ[2], bNI[2], bNH[2];
#pragma unroll
    for (int t = 0; t < 2; ++t) {
        int cb = g * 32 + t * 16 + (tcol & 12);
        bR[t] = be[cb]; bZ[t] = be[cb + 1]; bNI[t] = be[cb + 2]; bNH[t] = be[cb + 3];
    }
    __syncthreads();

    const int rowA = wv * 16 + tcol;                 // A-frag row (wave's M-tile)
    const int rowE = wv * 16 + 4 * quad + jr;        // epilogue-owned row
    float hprev[2] = {0.f, 0.f};
    f32x4 acc[2];

    auto ldsb = [&](int t, int kt) -> bf16x8 {
        b8u u;
        const __bf16* p = &sWh[t][tcol][kt * 32 + kq];
        u.q[0] = *(const u64*)p; u.q[1] = *(const u64*)(p + 4);
        return u.v;
    };
    auto xwin = [&](int s) {
        acc[0] = f32x4{0, 0, 0, 0}; acc[1] = f32x4{0, 0, 0, 0};
#pragma unroll
        for (int kt = 0; kt < 4; ++kt) {
            b8u b0, b1;
            const __bf16* p0 = &sWx[0][tcol][kt * 32 + kq];
            const __bf16* p1 = &sWx[1][tcol][kt * 32 + kq];
            b0.q[0] = *(const u64*)p0; b0.q[1] = *(const u64*)(p0 + 4);
            b1.q[0] = *(const u64*)p1; b1.q[1] = *(const u64*)(p1 + 4);
            bf16x8 a = *(const bf16x8*)(xb + (size_t)rowA * 65536 + s * 128 + kt * 32 + kq);
            acc[0] = MFMA16(a, b0.v, acc[0]);
            acc[1] = MFMA16(a, b1.v, acc[1]);
        }
    };
    auto tp4 = [&](f32x4& a) {                       // 4x4 lane transpose (r5-verified)
        bool s0 = tcol & 1, s1 = tcol & 2;
        float v;
        v = __shfl_xor(s0 ? a[0] : a[1], 1); if (s0) a[0] = v; else a[1] = v;
        v = __shfl_xor(s0 ? a[2] : a[3], 1); if (s0) a[2] = v; else a[3] = v;
        v = __shfl_xor(s1 ? a[0] : a[2], 2); if (s1) a[0] = v; else a[2] = v;
        v = __shfl_xor(s1 ? a[1] : a[3], 2); if (s1) a[1] = v; else a[3] = v;
    };

    xwin(0);
    for (int s = 0; s < 512; ++s) {
        const __bf16* hc = ring + (size_t)s * SLOT;          // plain cached reads (write-once slot)
        unsigned* hn = (unsigned*)ring + (size_t)(s + 1) * (SLOT / 2);
#pragma unroll 8
        for (int kt = 0; kt < 32; ++kt) {
            bf16x8 b0 = ldsb(0, kt), b1 = ldsb(1, kt);
            bf16x8 a = *(const bf16x8*)(hc + (size_t)rowA * 1024 + kt * 32 + kq);
            acc[0] = MFMA16(a, b0, acc[0]);
            acc[1] = MFMA16(a, b1, acc[1]);
        }
        tp4(acc[0]); tp4(acc[1]);
        pk2 p;
#pragma unroll
        for (int t = 0; t < 2; ++t) {
            float r = 1.f / (1.f + __expf(-(acc[t][0] + bR[t])));
            float z = 1.f / (1.f + __expf(-(acc[t][1] + bZ[t])));
            float n = tanhf(acc[t][2] + bNI[t] + r * (acc[t][3] + bNH[t]));
            float h = (1.f - z) * n + z * hprev[t];
            hprev[t] = h;
            p.h[t] = (__bf16)h;
        }
        __hip_atomic_store(hn + rowE * 512 + g * 4 + q, p.u,
                           __ATOMIC_RELAXED, __HIP_MEMORY_SCOPE_AGENT);
        if (s == 511) {
#pragma unroll
            for (int t = 0; t < 2; ++t)
                __hip_atomic_store(h32 + rowE * 1024 + g * 8 + q * 2 + t, hprev[t],
                                   __ATOMIC_RELAXED, __HIP_MEMORY_SCOPE_AGENT);
        }
        if (s < 511) {
            __syncthreads();             // compiler emits vmcnt(0): write-through stores at LLC
            bar_arrive(ctr, g);
            xwin(s + 1);                 // overlap next x-GEMM with grid convergence
            bar_wait(ctr, (unsigned)(s + 1) * NWG);
        }
    }
}

// ---------------- decoder ----------------
__global__ __launch_bounds__(THR, 1) void k_dec(
    const __bf16* __restrict__ Wd, const float* __restrict__ bd,
    const __bf16* __restrict__ Wo, const float* __restrict__ bo,
    __bf16* __restrict__ ring, const float* __restrict__ h32,
    float* __restrict__ out, unsigned* __restrict__ ctr) {
    __shared__ __bf16 sWh[2][16][WSTR];
    __shared__ __bf16 sWo[16][WSTR];
    const int g = blockIdx.x, tid = threadIdx.x;
    const int lane = tid & 63, wv = tid >> 6;
    const int tcol = lane & 15, quad = lane >> 4, kq = quad * 8;
    const int q = tcol >> 2, jr = tcol & 3;
    const bool has_out = (g < 8);

    for (int i = tid; i < 8192; i += THR) {
        int t = i >> 12, rem = i & 4095, tc = rem >> 8, k4 = rem & 255;
        *(u64*)&sWh[t][tc][k4 * 4] = *(const u64*)(Wd + ((size_t)(g * 2 + t) * 16 + tc) * 1024 + k4 * 4);
    }
    if (has_out) {
        for (int i = tid; i < 4096; i += THR) {
            int tc = i >> 8, k4 = i & 255;
            *(u64*)&sWo[tc][k4 * 4] = *(const u64*)(Wo + ((size_t)g * 16 + tc) * 1024 + k4 * 4);
        }
    }
    float bR[2], bZ[2], bNI[2], bNH[2];
#pragma unroll
    for (int t = 0; t < 2; ++t) {
        int cb = g * 32 + t * 16 + (tcol & 12);
        bR[t] = bd[cb]; bZ[t] = bd[cb + 1]; bNI[t] = bd[cb + 2]; bNH[t] = bd[cb + 3];
    }
    const float bo_v = has_out ? bo[g * 16 + tcol] : 0.f;

    const int rowA = wv * 16 + tcol;
    const int rowE = wv * 16 + 4 * quad + jr;
    float hprev[2];
#pragma unroll
    for (int t = 0; t < 2; ++t)
        hprev[t] = h32[rowE * 1024 + g * 8 + q * 2 + t];   // cross-kernel: launch-acquire fresh
    __syncthreads();

    auto ldsb = [&](const __bf16* p) -> bf16x8 {
        b8u u;
        u.q[0] = *(const u64*)p; u.q[1] = *(const u64*)(p + 4);
        return u.v;
    };
    auto tp4 = [&](f32x4& a) {
        bool s0 = tcol & 1, s1 = tcol & 2;
        float v;
        v = __shfl_xor(s0 ? a[0] : a[1], 1); if (s0) a[0] = v; else a[1] = v;
        v = __shfl_xor(s0 ? a[2] : a[3], 1); if (s0) a[2] = v; else a[3] = v;
        v = __shfl_xor(s1 ? a[0] : a[2], 2); if (s1) a[0] = v; else a[2] = v;
        v = __shfl_xor(s1 ? a[1] : a[3], 2); if (s1) a[1] = v; else a[3] = v;
    };

    for (int s = 0; s < 512; ++s) {
        const int rd = s ? (s - 1) : 512;                    // h^d_s slot
        const __bf16* hc = ring + (size_t)rd * SLOT;
        unsigned* hn = (unsigned*)ring + (size_t)s * (SLOT / 2);   // h^d_{s+1} slot
        f32x4 acc0 = {0, 0, 0, 0}, acc1 = {0, 0, 0, 0}, acc2 = {0, 0, 0, 0};
#pragma unroll 8
        for (int kt = 0; kt < 32; ++kt) {
            bf16x8 b0 = ldsb(&sWh[0][tcol][kt * 32 + kq]);
            bf16x8 b1 = ldsb(&sWh[1][tcol][kt * 32 + kq]);
            bf16x8 a = *(const bf16x8*)(hc + (size_t)rowA * 1024 + kt * 32 + kq);
            acc0 = MFMA16(a, b0, acc0);
            acc1 = MFMA16(a, b1, acc1);
            if (has_out) acc2 = MFMA16(a, ldsb(&sWo[tcol][kt * 32 + kq]), acc2);
        }
        // out[:, 512-s, :] = W_out h^d_s + b_out  (valid s>=1); plain cached stores
        if (has_out && s >= 1) {
#pragma unroll
            for (int i = 0; i < 4; ++i) {
                int row = wv * 16 + quad * 4 + i;
                out[(size_t)row * 65536 + (size_t)(512 - s) * 128 + g * 16 + tcol] = acc2[i] + bo_v;
            }
        }
        tp4(acc0); tp4(acc1);
        f32x4 ac[2] = {acc0, acc1};
        pk2 p;
#pragma unroll
        for (int t = 0; t < 2; ++t) {
            float r = 1.f / (1.f + __expf(-(ac[t][0] + bR[t])));
            float z = 1.f / (1.f + __expf(-(ac[t][1] + bZ[t])));
            float n = tanhf(ac[t][2] + bNI[t] + r * (ac[t][3] + bNH[t]));
            float h = (1.f - z) * n + z * hprev[t];
            hprev[t] = h;
            p.h[t] = (__bf16)h;
        }
        __hip_atomic_store(hn + rowE * 512 + g * 4 + q, p.u,
                           __ATOMIC_RELAXED, __HIP_MEMORY_SCOPE_AGENT);
        __syncthreads();                 // drain write-through h stores
        bar_arrive(ctr, g);
        if (s < 511) bar_wait(ctr, (unsigned)(s + 1) * NWG);
    }
    // final out pass: out[:, 0, :] = W_out h^d_512 + b_out (slot 511)
    if (has_out) {
        bar_wait(ctr, 512u * NWG);
        const __bf16* hc = ring + (size_t)511 * SLOT;
        f32x4 acc2 = {0, 0, 0, 0};
#pragma unroll 8
        for (int kt = 0; kt < 32; ++kt) {
            bf16x8 a = *(const bf16x8*)(hc + (size_t)rowA * 1024 + kt * 32 + kq);
            acc2 = MFMA16(a, ldsb(&sWo[tcol][kt * 32 + kq]), acc2);
        }
#pragma unroll
        for (int i = 0; i < 4; ++i) {
            int row = wv * 16 + quad * 4 + i;
            out[(size_t)row * 65536 + g * 16 + tcol] = acc2[i] + bo_v;
        }
    }
}

// ---------------- launch ----------------
extern "C" void kernel_launch(void* const* d_in, const int* in_sizes, int n_in,
                              void* d_out, int out_size, void* d_ws, size_t ws_size,
                              hipStream_t stream) {
    (void)in_sizes; (void)n_in; (void)out_size; (void)ws_size;
    const float* x    = (const float*)d_in[0];
    const float* Wihe = (const float*)d_in[1];
    const float* Whhe = (const float*)d_in[2];
    const float* bihe = (const float*)d_in[3];
    const float* bhhe = (const float*)d_in[4];
    const float* Wihd = (const float*)d_in[5];
    const float* Whhd = (const float*)d_in[6];
    const float* bihd = (const float*)d_in[7];
    const float* bhhd = (const float*)d_in[8];
    const float* Wout = (const float*)d_in[9];
    const float* bout = (const float*)d_in[10];

    char* ws = (char*)d_ws;
    __bf16*   ring = (__bf16*)(ws + O_RING);
    float*    h32  = (float*)(ws + O_H32);
    unsigned* ctr  = (unsigned*)(ws + O_CTR);
    __bf16*   xbf  = (__bf16*)(ws + O_XB);
    __bf16*   Weh  = (__bf16*)(ws + O_WEH);
    __bf16*   Wex  = (__bf16*)(ws + O_WEX);
    float*    be   = (float*)(ws + O_BE);
    __bf16*   Wd   = (__bf16*)(ws + O_WD);
    float*    bd   = (float*)(ws + O_BD);
    __bf16*   Wo   = (__bf16*)(ws + O_WO);
    float*    bo   = (float*)(ws + O_BO);
    __bf16*   Wc   = (__bf16*)(ws + O_WC);

    hipMemsetAsync(ring, 0, 262144, stream);         // slot 0 = h_0 = 0
    hipMemsetAsync(ctr, 0, 8192, stream);            // barrier counters

    k_xcvt<<<4096, 256, 0, stream>>>(x, xbf, B_ * S_ * 128);
    k_pack_enc<<<NWG, 256, 0, stream>>>(Wihe, Whhe, bihe, bhhe, Weh, Wex, be);
    k_wcomb<<<384, 256, 0, stream>>>(Wihd, Wout, Wc);
    k_pack_dec<<<NWG, 256, 0, stream>>>(Whhd, Wc, Wihd, bihd, bhhd, bout, Wd, bd);
    k_pack_out<<<8, 256, 0, stream>>>(Wout, bout, Wo, bo);

    k_enc<<<NWG, THR, 0, stream>>>(xbf, Weh, Wex, be, ring, h32, ctr);
    k_dec<<<NWG, THR, 0, stream>>>(Wd, bd, Wo, bo, ring, h32, (float*)d_out, ctr + 1024);
}